// Round 1
// baseline (10102.250 us; speedup 1.0000x reference)
//
#include <hip/hip_runtime.h>
#include <cstdint>
#include <cstddef>

#define BS 8
#define TT 256
#define DD 2048
#define NN 8192
#define KK 64
#define GG 512
#define GSZ 16
#define HH 64
#define MIN_ 69
#define MOUT_ 66
#define NSL 32     // slices per batch
#define SLN 256    // neurons per slice

// ---------------- Phase A: modulator (runs once) ----------------
__global__ __launch_bounds__(256) void modulator_kernel(
    const float* __restrict__ w1, const float* __restrict__ b1,
    const float* __restrict__ w2, const float* __restrict__ b2,
    const float* __restrict__ act0, const float* __restrict__ heb0,
    const float* __restrict__ dec0, const float* __restrict__ thr0,
    const float* __restrict__ nid,
    float* __restrict__ wconn, float* __restrict__ decayB, float* __restrict__ thrB)
{
  const int g = blockIdx.x, b = blockIdx.y, tid = threadIdx.x;
  __shared__ float xs[GSZ][MIN_];
  __shared__ float hd[GSZ][HH];

  const int nbase = g * GSZ;
  // mod_in = [act(1), hebbian(64), decay(1), threshold(1), nid(2)]
  for (int j = tid; j < GSZ * KK; j += 256) {
    int s = j >> 6, k = j & 63;
    xs[s][1 + k] = heb0[((size_t)(b * NN + nbase + s)) * KK + k];
  }
  if (tid < GSZ) {
    int n = nbase + tid;
    xs[tid][0]  = act0[b * NN + n];
    xs[tid][65] = dec0[b * NN + n];
    xs[tid][66] = thr0[b * NN + n];
    xs[tid][67] = nid[2 * n];
    xs[tid][68] = nid[2 * n + 1];
  }
  __syncthreads();

  // hdn[s][h] = tanh(sum_i xs[s][i]*w1[g][i][h] + b1[g][h])
  for (int rep = 0; rep < 4; ++rep) {
    int t2 = tid + rep * 256;
    int s = t2 >> 6, h = t2 & 63;
    float acc = b1[g * HH + h];
    const float* w1g = w1 + (size_t)g * MIN_ * HH + h;
    for (int i = 0; i < MIN_; ++i) acc = fmaf(xs[s][i], w1g[(size_t)i * HH], acc);
    hd[s][h] = tanhf(acc);
  }
  __syncthreads();

  // out[s][o] = sum_h hd[s][h]*w2[g][h][o] + b2[g][o]
  for (int j = tid; j < GSZ * MOUT_; j += 256) {
    int s = j / MOUT_, o = j - s * MOUT_;
    float acc = b2[g * MOUT_ + o];
    const float* w2g = w2 + (size_t)g * HH * MOUT_ + o;
    for (int h = 0; h < HH; ++h) acc = fmaf(hd[s][h], w2g[(size_t)h * MOUT_], acc);
    int gidx = b * NN + nbase + s;
    if (o < KK)       wconn[(size_t)gidx * KK + o] = acc;
    else if (o == KK) decayB[gidx] = 1.f / (1.f + expf(-acc));
    else              thrB[gidx]   = acc;
  }
}

// ---------------- Phase B: 256-step recurrent scan ----------------
// 256 WGs (8 batches x 32 slices), 256 threads, 1 neuron/thread.
// Full batch act copy in LDS; per-step exchange via flag-guarded double buffer.
__global__ __launch_bounds__(256, 1) void scan_kernel(
    const float* __restrict__ cc, const int* __restrict__ conn,
    const float* __restrict__ V0, const float* __restrict__ act0,
    const float* __restrict__ wconn, const float* __restrict__ decayB,
    const float* __restrict__ thrB,
    float* __restrict__ out, float* __restrict__ actbuf, int* __restrict__ flags)
{
  const int tid = threadIdx.x;
  const int b  = blockIdx.x >> 5;
  const int sl = blockIdx.x & 31;
  const int n    = sl * SLN + tid;
  const int gidx = b * NN + n;

  __shared__ float alds[NN];   // 32 KB: full act of batch b

  // persistent per-thread state in VGPRs
  float w[KK];
  int   ad[KK];
  {
    const float4* wr = reinterpret_cast<const float4*>(wconn + (size_t)gidx * KK);
    #pragma unroll
    for (int j = 0; j < KK / 4; ++j) {
      float4 v = wr[j];
      w[4*j+0] = v.x; w[4*j+1] = v.y; w[4*j+2] = v.z; w[4*j+3] = v.w;
    }
    const int4* ir = reinterpret_cast<const int4*>(conn + (size_t)n * KK);
    #pragma unroll
    for (int j = 0; j < KK / 4; ++j) {
      int4 v = ir[j];
      ad[4*j+0] = v.x; ad[4*j+1] = v.y; ad[4*j+2] = v.z; ad[4*j+3] = v.w;
    }
  }
  float V     = V0[gidx];
  float dec   = decayB[gidx];
  float onemd = 1.f - dec;
  float thr   = thrB[gidx];

  // initial act into LDS
  {
    const float4* src = reinterpret_cast<const float4*>(act0 + (size_t)b * NN);
    float4* dst = reinterpret_cast<float4*>(alds);
    #pragma unroll
    for (int j = 0; j < 8; ++j) dst[tid + j * 256] = src[tid + j * 256];
  }
  __syncthreads();

  for (int t = 0; t < TT; ++t) {
    float inj = cc[((size_t)b * TT + t) * DD + (n >> 2)];

    // gather + dot over 64 random neighbors (LDS)
    float s0 = 0.f, s1 = 0.f, s2 = 0.f, s3 = 0.f;
    #pragma unroll
    for (int k = 0; k < KK; k += 4) {
      s0 = fmaf(alds[ad[k+0]], w[k+0], s0);
      s1 = fmaf(alds[ad[k+1]], w[k+1], s1);
      s2 = fmaf(alds[ad[k+2]], w[k+2], s2);
      s3 = fmaf(alds[ad[k+3]], w[k+3], s3);
    }
    float recv = (s0 + s1) + (s2 + s3) + inj;
    V = dec * V + onemd * recv;
    float x = V - thr;
    float a = 1.f / (1.f + expf(-x));

    // fused output: mean over groups of 4 neurons
    float p = a + __shfl_xor(a, 1);
    p = p + __shfl_xor(p, 2);
    if ((tid & 3) == 0)
      out[((size_t)b * TT + t) * DD + sl * 64 + (tid >> 2)] = 0.25f * p;

    if (t != TT - 1) {
      const int pw = t & 1;
      // publish slice
      actbuf[pw * (BS * NN) + gidx] = a;
      __threadfence();                 // agent-scope release of data
      __syncthreads();
      if (tid == 0)
        __hip_atomic_store(&flags[(pw * BS + b) * NSL + sl], t + 1,
                           __ATOMIC_RELEASE, __HIP_MEMORY_SCOPE_AGENT);

      // wait for all 32 slices of this batch
      int* fl = flags + (pw * BS + b) * NSL;
      for (;;) {
        int v = __hip_atomic_load(fl + (tid & 31), __ATOMIC_RELAXED,
                                  __HIP_MEMORY_SCOPE_AGENT);
        if (__all(v >= t + 1)) break;
      }
      __syncthreads();
      __threadfence();                 // acquire: invalidate stale cache lines

      // coalesced reload of full batch act into LDS
      const float4* src = reinterpret_cast<const float4*>(actbuf + pw * (BS * NN) + (size_t)b * NN);
      float4* dst = reinterpret_cast<float4*>(alds);
      #pragma unroll
      for (int j = 0; j < 8; ++j) dst[tid + j * 256] = src[tid + j * 256];
      __syncthreads();
    }
  }
}

extern "C" void kernel_launch(void* const* d_in, const int* in_sizes, int n_in,
                              void* d_out, int out_size, void* d_ws, size_t ws_size,
                              hipStream_t stream)
{
  const float* cc   = (const float*)d_in[0];
  const float* w1   = (const float*)d_in[1];
  const float* b1   = (const float*)d_in[2];
  const float* w2   = (const float*)d_in[3];
  const float* b2   = (const float*)d_in[4];
  const int*   conn = (const int*)d_in[5];
  const float* nid  = (const float*)d_in[6];
  const float* V0   = (const float*)d_in[7];
  const float* act0 = (const float*)d_in[8];
  const float* heb0 = (const float*)d_in[9];
  const float* dec0 = (const float*)d_in[10];
  const float* thr0 = (const float*)d_in[11];
  float* out = (float*)d_out;

  char* ws = (char*)d_ws;
  float* wconn  = (float*)ws;                               // 8*8192*64 f32 = 16 MB
  float* decayB = (float*)(ws + (size_t)BS * NN * KK * 4);  // 8*8192
  float* thrB   = decayB + BS * NN;                         // 8*8192
  float* actbuf = thrB + BS * NN;                           // 2*8*8192
  int*   flags  = (int*)(actbuf + 2 * BS * NN);             // 2*8*32

  hipMemsetAsync(flags, 0, 2 * BS * NSL * sizeof(int), stream);

  dim3 gA(GG, BS);
  modulator_kernel<<<gA, 256, 0, stream>>>(w1, b1, w2, b2, act0, heb0, dec0, thr0,
                                           nid, wconn, decayB, thrB);
  scan_kernel<<<dim3(BS * NSL), 256, 0, stream>>>(cc, conn, V0, act0, wconn,
                                                  decayB, thrB, out, actbuf, flags);
}

// Round 2
// 2901.164 us; speedup vs baseline: 3.4821x; 3.4821x over previous
//
#include <hip/hip_runtime.h>
#include <cstdint>
#include <cstddef>

#define BS 8
#define TT 256
#define DD 2048
#define NN 8192
#define KK 64
#define GG 512
#define GSZ 16
#define HH 64
#define MIN_ 69
#define MOUT_ 66
#define NSL 32     // slices per batch
#define SLN 256    // neurons per slice

// ---------------- Phase A: modulator (runs once) ----------------
__global__ __launch_bounds__(256) void modulator_kernel(
    const float* __restrict__ w1, const float* __restrict__ b1,
    const float* __restrict__ w2, const float* __restrict__ b2,
    const float* __restrict__ act0, const float* __restrict__ heb0,
    const float* __restrict__ dec0, const float* __restrict__ thr0,
    const float* __restrict__ nid,
    float* __restrict__ wconn, float* __restrict__ decayB, float* __restrict__ thrB)
{
  const int g = blockIdx.x, b = blockIdx.y, tid = threadIdx.x;
  __shared__ float xs[GSZ][MIN_];
  __shared__ float hd[GSZ][HH];

  const int nbase = g * GSZ;
  // mod_in = [act(1), hebbian(64), decay(1), threshold(1), nid(2)]
  for (int j = tid; j < GSZ * KK; j += 256) {
    int s = j >> 6, k = j & 63;
    xs[s][1 + k] = heb0[((size_t)(b * NN + nbase + s)) * KK + k];
  }
  if (tid < GSZ) {
    int n = nbase + tid;
    xs[tid][0]  = act0[b * NN + n];
    xs[tid][65] = dec0[b * NN + n];
    xs[tid][66] = thr0[b * NN + n];
    xs[tid][67] = nid[2 * n];
    xs[tid][68] = nid[2 * n + 1];
  }
  __syncthreads();

  // hdn[s][h] = tanh(sum_i xs[s][i]*w1[g][i][h] + b1[g][h])
  for (int rep = 0; rep < 4; ++rep) {
    int t2 = tid + rep * 256;
    int s = t2 >> 6, h = t2 & 63;
    float acc = b1[g * HH + h];
    const float* w1g = w1 + (size_t)g * MIN_ * HH + h;
    for (int i = 0; i < MIN_; ++i) acc = fmaf(xs[s][i], w1g[(size_t)i * HH], acc);
    hd[s][h] = tanhf(acc);
  }
  __syncthreads();

  // out[s][o] = sum_h hd[s][h]*w2[g][h][o] + b2[g][o]
  for (int j = tid; j < GSZ * MOUT_; j += 256) {
    int s = j / MOUT_, o = j - s * MOUT_;
    float acc = b2[g * MOUT_ + o];
    const float* w2g = w2 + (size_t)g * HH * MOUT_ + o;
    for (int h = 0; h < HH; ++h) acc = fmaf(hd[s][h], w2g[(size_t)h * MOUT_], acc);
    int gidx = b * NN + nbase + s;
    if (o < KK)       wconn[(size_t)gidx * KK + o] = acc;
    else if (o == KK) decayB[gidx] = 1.f / (1.f + expf(-acc));
    else              thrB[gidx]   = acc;
  }
}

// ---------------- Phase B: 256-step recurrent scan ----------------
// 256 WGs (8 batches x 32 slices), 256 threads, 1 neuron/thread.
// Exchange via write-through (sc1) agent-scope atomics: NO fences, NO L2
// writeback/invalidate. Ordering: data stores -> s_waitcnt vmcnt(0) ->
// __syncthreads -> flag store. Readers poll flags (sc1 loads), then read
// data with sc1 loads (served at the coherent point, L2 never stale).
__global__ __launch_bounds__(256, 1) void scan_kernel(
    const float* __restrict__ cc, const int* __restrict__ conn,
    const float* __restrict__ V0, const float* __restrict__ act0,
    const float* __restrict__ wconn, const float* __restrict__ decayB,
    const float* __restrict__ thrB,
    float* __restrict__ out, float* __restrict__ actbuf, int* __restrict__ flags)
{
  const int tid = threadIdx.x;
  const int b  = blockIdx.x >> 5;
  const int sl = blockIdx.x & 31;
  const int n    = sl * SLN + tid;
  const int gidx = b * NN + n;

  __shared__ float alds[NN];   // 32 KB: full act of batch b

  // persistent per-thread state in VGPRs/AGPRs
  float w[KK];
  int   ad[KK];
  {
    const float4* wr = reinterpret_cast<const float4*>(wconn + (size_t)gidx * KK);
    #pragma unroll
    for (int j = 0; j < KK / 4; ++j) {
      float4 v = wr[j];
      w[4*j+0] = v.x; w[4*j+1] = v.y; w[4*j+2] = v.z; w[4*j+3] = v.w;
    }
    const int4* ir = reinterpret_cast<const int4*>(conn + (size_t)n * KK);
    #pragma unroll
    for (int j = 0; j < KK / 4; ++j) {
      int4 v = ir[j];
      ad[4*j+0] = v.x; ad[4*j+1] = v.y; ad[4*j+2] = v.z; ad[4*j+3] = v.w;
    }
  }
  float V     = V0[gidx];
  float dec   = decayB[gidx];
  float onemd = 1.f - dec;
  float thr   = thrB[gidx];

  // initial act into LDS
  {
    const float4* src = reinterpret_cast<const float4*>(act0 + (size_t)b * NN);
    float4* dst = reinterpret_cast<float4*>(alds);
    #pragma unroll
    for (int j = 0; j < 8; ++j) dst[tid + j * 256] = src[tid + j * 256];
  }
  __syncthreads();

  for (int t = 0; t < TT; ++t) {
    float inj = cc[((size_t)b * TT + t) * DD + (n >> 2)];

    // gather + dot over 64 random neighbors (LDS)
    float s0 = 0.f, s1 = 0.f, s2 = 0.f, s3 = 0.f;
    #pragma unroll
    for (int k = 0; k < KK; k += 4) {
      s0 = fmaf(alds[ad[k+0]], w[k+0], s0);
      s1 = fmaf(alds[ad[k+1]], w[k+1], s1);
      s2 = fmaf(alds[ad[k+2]], w[k+2], s2);
      s3 = fmaf(alds[ad[k+3]], w[k+3], s3);
    }
    float recv = (s0 + s1) + (s2 + s3) + inj;
    V = dec * V + onemd * recv;
    float x = V - thr;
    float a = 1.f / (1.f + expf(-x));

    if (t != TT - 1) {
      const int pw = t & 1;
      // publish slice value (write-through, agent-coherent)
      __hip_atomic_store(&actbuf[pw * (BS * NN) + gidx], a,
                         __ATOMIC_RELAXED, __HIP_MEMORY_SCOPE_AGENT);

      // fused output while the store is in flight
      float p = a + __shfl_xor(a, 1);
      p = p + __shfl_xor(p, 2);
      if ((tid & 3) == 0)
        out[((size_t)b * TT + t) * DD + sl * 64 + (tid >> 2)] = 0.25f * p;

      // all of this wave's stores acked at the coherent point
      asm volatile("s_waitcnt vmcnt(0)" ::: "memory");
      __syncthreads();   // ...and all waves of the WG past their waitcnt
      if (tid == 0)
        __hip_atomic_store(&flags[(pw * BS + b) * NSL + sl], t + 1,
                           __ATOMIC_RELAXED, __HIP_MEMORY_SCOPE_AGENT);

      // wait for all 32 slices of this batch
      int* fl = flags + (pw * BS + b) * NSL;
      for (;;) {
        int v = __hip_atomic_load(fl + (tid & 31), __ATOMIC_RELAXED,
                                  __HIP_MEMORY_SCOPE_AGENT);
        if (__all(v >= t + 1)) break;
      }
      asm volatile("" ::: "memory");

      // reload full batch act into LDS via coherent (sc1) loads
      const float* src = actbuf + pw * (BS * NN) + (size_t)b * NN;
      #pragma unroll
      for (int j = 0; j < 32; ++j) {
        int idx = tid + j * 256;
        alds[idx] = __hip_atomic_load(src + idx, __ATOMIC_RELAXED,
                                      __HIP_MEMORY_SCOPE_AGENT);
      }
      __syncthreads();
    } else {
      // last step: output only
      float p = a + __shfl_xor(a, 1);
      p = p + __shfl_xor(p, 2);
      if ((tid & 3) == 0)
        out[((size_t)b * TT + t) * DD + sl * 64 + (tid >> 2)] = 0.25f * p;
    }
  }
}

extern "C" void kernel_launch(void* const* d_in, const int* in_sizes, int n_in,
                              void* d_out, int out_size, void* d_ws, size_t ws_size,
                              hipStream_t stream)
{
  const float* cc   = (const float*)d_in[0];
  const float* w1   = (const float*)d_in[1];
  const float* b1   = (const float*)d_in[2];
  const float* w2   = (const float*)d_in[3];
  const float* b2   = (const float*)d_in[4];
  const int*   conn = (const int*)d_in[5];
  const float* nid  = (const float*)d_in[6];
  const float* V0   = (const float*)d_in[7];
  const float* act0 = (const float*)d_in[8];
  const float* heb0 = (const float*)d_in[9];
  const float* dec0 = (const float*)d_in[10];
  const float* thr0 = (const float*)d_in[11];
  float* out = (float*)d_out;

  char* ws = (char*)d_ws;
  float* wconn  = (float*)ws;                               // 8*8192*64 f32 = 16 MB
  float* decayB = (float*)(ws + (size_t)BS * NN * KK * 4);  // 8*8192
  float* thrB   = decayB + BS * NN;                         // 8*8192
  float* actbuf = thrB + BS * NN;                           // 2*8*8192
  int*   flags  = (int*)(actbuf + 2 * BS * NN);             // 2*8*32

  hipMemsetAsync(flags, 0, 2 * BS * NSL * sizeof(int), stream);

  dim3 gA(GG, BS);
  modulator_kernel<<<gA, 256, 0, stream>>>(w1, b1, w2, b2, act0, heb0, dec0, thr0,
                                           nid, wconn, decayB, thrB);
  scan_kernel<<<dim3(BS * NSL), 256, 0, stream>>>(cc, conn, V0, act0, wconn,
                                                  decayB, thrB, out, actbuf, flags);
}